// Round 1
// 474.364 us; speedup vs baseline: 1.0261x; 1.0261x over previous
//
#include <hip/hip_runtime.h>
#include <math.h>

typedef __attribute__((ext_vector_type(8))) short short8;
typedef __attribute__((ext_vector_type(4))) float f32x4;
typedef unsigned short ushort;
typedef unsigned int uint;

// Problem constants
#define NB   128
#define CIN  2048
#define PP   256
#define KK   16
#define CO   256
#define DO   512

// ws layout (float offsets)
#define WS_PARTIAL 0          // [128][32][256] = 1,048,576 floats
#define WS_POS     1048576    // 2048 ints
#define WS_LNORM   1050624    // 32768 floats
#define WS_NODES   1083392    // bf16 [2048 m][2048 c] = 8 MB = 2,097,152 slots
#define WS_WB      3180544    // bf16 [256 o][2048 c] = 1 MB = 262,144 slots
#define WS_XPART   3442688    // 8 x [2048 m][256 o] fp32 = 4,194,304
#define WS_Y       7636992    // [128][4096] fp32 = 524,288

__device__ __forceinline__ ushort f2bf(float f) {
    uint u = __builtin_bit_cast(uint, f);
    u += 0x7fffu + ((u >> 16) & 1u);   // RNE (inputs are normal floats)
    return (ushort)(u >> 16);
}

// ---------------------------------------------------------------------------
// K0: prep — convert conv_w to bf16 AND init out with fc bias. grid 768.
__global__ __launch_bounds__(256) void k_prep(const float* __restrict__ conv_w,
                                              ushort* __restrict__ Wb,
                                              const float* __restrict__ fcb,
                                              float* __restrict__ out) {
    int b = blockIdx.x, t = threadIdx.x;
    if (b < 512) {
        int idx = (b * 256 + t) * 4;
        float4 v = *(const float4*)(conv_w + idx);
        uint2 u;
        u.x = (uint)f2bf(v.x) | ((uint)f2bf(v.y) << 16);
        u.y = (uint)f2bf(v.z) | ((uint)f2bf(v.w) << 16);
        *(uint2*)(Wb + idx) = u;
    } else {
        int i = (b - 512) * 256 + t;
        out[i] = fcb[i & 511];
    }
}

// ---------------------------------------------------------------------------
// K1: partial channel-sum. grid (128, 8), block 256. Streams all 256 MB once.
__global__ __launch_bounds__(256) void k_reduce(const float* __restrict__ snd,
                                                float* __restrict__ partial) {
    int n = blockIdx.x, chunk = blockIdx.y, t = threadIdx.x;
    int sub = t >> 6, p4 = t & 63;
    const float4* base = (const float4*)(snd + (size_t)n * CIN * PP
                                         + (size_t)(chunk * 256 + sub * 64) * PP) + p4;
    float4 acc = make_float4(0.f, 0.f, 0.f, 0.f);
#pragma unroll 4
    for (int c = 0; c < 64; ++c) {
        float4 v = base[c * 64];
        acc.x += v.x; acc.y += v.y; acc.z += v.z; acc.w += v.w;
    }
    ((float4*)(partial + (size_t)(n * 32 + chunk * 4 + sub) * 256))[p4] = acc;
}

// ---------------------------------------------------------------------------
// K2: finish reduction, top-16 (shuffle butterfly), remap, lnorm. grid 128.
__global__ __launch_bounds__(256) void k_topk_lnorm(const float* __restrict__ partial,
                                                    int* __restrict__ pos,
                                                    float* __restrict__ lnorm) {
    int n = blockIdx.x, t = threadIdx.x;
    int lane = t & 63, wv = t >> 6;
    __shared__ float wval[4];
    __shared__ int   widx[4];
    __shared__ int   sel[16];
    __shared__ float rr[16], cc[16], dinv[16];
    __shared__ float Ash[256];

    float v = 0.f;
#pragma unroll 8
    for (int j = 0; j < 32; ++j) v += partial[(size_t)(n * 32 + j) * 256 + t];

    for (int k = 0; k < 16; ++k) {
        float bv = v; int bi = t;
#pragma unroll
        for (int off = 32; off > 0; off >>= 1) {
            float ov = __shfl_xor(bv, off, 64);
            int   oi = __shfl_xor(bi, off, 64);
            if (ov > bv || (ov == bv && oi < bi)) { bv = ov; bi = oi; }
        }
        if (lane == 0) { wval[wv] = bv; widx[wv] = bi; }
        __syncthreads();
        float best = wval[0]; int besti = widx[0];
#pragma unroll
        for (int w = 1; w < 4; ++w) {
            float ww = wval[w]; int wi = widx[w];
            if (ww > best || (ww == best && wi < besti)) { best = ww; besti = wi; }
        }
        if (t == besti) v = -INFINITY;
        if (t == 0) sel[k] = besti;
        __syncthreads();
    }

    if (t < 16) {
        int idx = sel[t];
        int r = (idx < 16) ? (idx >> 4) : ((idx >> 4) - 1);
        int c = ((idx & 15) == 0) ? 15 : ((idx & 15) - 1);
        pos[n * 16 + t] = r * 16 + c;
        rr[t] = (float)r; cc[t] = (float)c;
    }
    __syncthreads();
    {
        int i = t >> 4, j = t & 15;
        float dr = rr[i] - rr[j], dc = cc[i] - cc[j];
        Ash[t] = expf(-(dr * dr + dc * dc) * (1.0f / 32.0f));
    }
    __syncthreads();
    if (t < 16) {
        float srow = 0.f;
#pragma unroll
        for (int j = 0; j < 16; ++j) srow += Ash[t * 16 + j];
        dinv[t] = rsqrtf(srow);
    }
    __syncthreads();
    {
        int i = t >> 4, j = t & 15;
        lnorm[(size_t)n * 256 + t] = Ash[t] * dinv[i] * dinv[j];
    }
}

// ---------------------------------------------------------------------------
// K3: STREAMING gather. grid (128 n, 64 cg), block 256 (4 waves).
// Each wave reads 8 full channel rows (1 KB each) fully coalesced
// (64 lanes x float4 = one row), extracts the 16 selected positions
// in-register via 4 shuffles + component select, stashes bf16 into a
// padded LDS tile, then the block writes nodes rows as coalesced 64 B
// segments. Converts the old 4 B-scatter (4.2M random lines) into a
// clean sequential stream of the same bytes.
__global__ __launch_bounds__(256) void k_gather(const float* __restrict__ snd,
                                                const int* __restrict__ pos,
                                                ushort* __restrict__ nodes) {
    int n = blockIdx.x, cg = blockIdx.y, t = threadIdx.x;
    int w = t >> 6, l = t & 63;
    __shared__ int lpos[16];
    __shared__ ushort Nsh[16][34];   // pad 34: write banks (k*17 + c/2)%32 distinct
    if (t < 16) lpos[t] = pos[n * 16 + t];
    __syncthreads();

    int p = lpos[l & 15];            // uniform across the four 16-lane groups
    int srclane = p >> 2;            // p in [0,239] -> srclane <= 59
    int comp = p & 3;

    const float4* rowbase = (const float4*)(snd + (size_t)n * CIN * PP
                                            + (size_t)(cg * 32 + w * 8) * PP);
    float4 vv[8];
#pragma unroll
    for (int cc = 0; cc < 8; ++cc) vv[cc] = rowbase[(size_t)cc * 64 + l];

#pragma unroll
    for (int cc = 0; cc < 8; ++cc) {
        float s0 = __shfl(vv[cc].x, srclane, 64);
        float s1 = __shfl(vv[cc].y, srclane, 64);
        float s2 = __shfl(vv[cc].z, srclane, 64);
        float s3 = __shfl(vv[cc].w, srclane, 64);
        float val = (comp & 2) ? ((comp & 1) ? s3 : s2)
                               : ((comp & 1) ? s1 : s0);
        if (l < 16) Nsh[l][w * 8 + cc] = f2bf(val);
    }
    __syncthreads();

    int kk = t >> 4, u = t & 15;
    uint pv = (uint)Nsh[kk][u * 2] | ((uint)Nsh[kk][u * 2 + 1] << 16);
    ((uint*)(nodes + (size_t)(n * 16 + kk) * 2048 + cg * 32))[u] = pv;
}

// ---------------------------------------------------------------------------
// K4: conv GEMM via bf16 MFMA 16x16x32, split-K (kc=8) for occupancy:
// grid (32, 4, 8) = 1024 blocks = 4 blocks/CU = 16 waves/CU.
// BK=64 (2 k-steps per staged tile -> half the barriers). LDS rows padded
// to 72 bf16 (144 B) -> conflict-free ds_read_b128 fragments.
__global__ __launch_bounds__(256) void k_conv(const ushort* __restrict__ nodes,
                                              const ushort* __restrict__ Wb,
                                              float* __restrict__ Xpart) {
    int bm = blockIdx.x, bo = blockIdx.y, kc = blockIdx.z, t = threadIdx.x;
    int w = t >> 6, l = t & 63;
    int lm = l & 15, quad = l >> 4;
    __shared__ ushort As[64 * 72];
    __shared__ ushort Bs[64 * 72];
    f32x4 acc[4] = {{0.f,0.f,0.f,0.f},{0.f,0.f,0.f,0.f},{0.f,0.f,0.f,0.f},{0.f,0.f,0.f,0.f}};
    int m0 = bm * 64, o0 = bo * 64;
    int srow = t >> 3, seg = t & 7;
    const ushort* ard = As + (w * 16 + lm) * 72 + quad * 8;
    const ushort* brd = Bs + lm * 72 + quad * 8;

    for (int c0 = kc * 256; c0 < kc * 256 + 256; c0 += 64) {
#pragma unroll
        for (int i = 0; i < 2; ++i) {
            int r = i * 32 + srow;
            *(uint4*)(As + r * 72 + seg * 8) =
                *(const uint4*)(nodes + (size_t)(m0 + r) * 2048 + c0 + seg * 8);
            *(uint4*)(Bs + r * 72 + seg * 8) =
                *(const uint4*)(Wb + (size_t)(o0 + r) * 2048 + c0 + seg * 8);
        }
        __syncthreads();
#pragma unroll
        for (int ks = 0; ks < 2; ++ks) {
            short8 af = *(const short8*)(ard + ks * 32);
#pragma unroll
            for (int ot = 0; ot < 4; ++ot) {
                short8 bf = *(const short8*)(brd + ot * 16 * 72 + ks * 32);
                acc[ot] = __builtin_amdgcn_mfma_f32_16x16x32_bf16(af, bf, acc[ot], 0, 0, 0);
            }
        }
        __syncthreads();
    }

    float* Xp = Xpart + (size_t)kc * 524288;
#pragma unroll
    for (int ot = 0; ot < 4; ++ot) {
        int o = o0 + ot * 16 + lm;
#pragma unroll
        for (int r = 0; r < 4; ++r) {
            int m = m0 + w * 16 + quad * 4 + r;   // C/D: row = quad*4 + reg
            Xp[(size_t)m * 256 + o] = acc[ot][r];
        }
    }
}

// ---------------------------------------------------------------------------
// K5: combine split-K partials + bias + relu + lnorm mix -> Y (fp32). grid 128.
__global__ __launch_bounds__(256) void k_xmix(const float* __restrict__ Xpart,
                                              const float* __restrict__ bias,
                                              const float* __restrict__ lnorm,
                                              float* __restrict__ Y) {
    int n = blockIdx.x, o = threadIdx.x;
    __shared__ float ln[256];
    ln[o] = lnorm[(size_t)n * 256 + o];
    float b = bias[o];
    __syncthreads();
    float xv[16];
#pragma unroll
    for (int j = 0; j < 16; ++j) {
        size_t off = (size_t)(n * 16 + j) * 256 + o;
        float s = b;
#pragma unroll
        for (int kc = 0; kc < 8; ++kc) s += Xpart[(size_t)kc * 524288 + off];
        xv[j] = fmaxf(s, 0.0f);
    }
#pragma unroll
    for (int i = 0; i < 16; ++i) {
        float a = 0.f;
#pragma unroll
        for (int j = 0; j < 16; ++j) a += ln[i * 16 + j] * xv[j];
        Y[(size_t)n * 4096 + i * 256 + o] = a;
    }
}

// ---------------------------------------------------------------------------
// K6: fc GEMM split-K fp32, atomic accumulate onto bias-initialized out.
// grid (4, 8, 16) = 512 blocks = 2 blocks/CU.
__global__ __launch_bounds__(256) void k_fc(const float* __restrict__ Y,
                                            const float* __restrict__ Fw,
                                            float* __restrict__ out) {
    int bn = blockIdx.x, bd = blockIdx.y, bk = blockIdx.z, t = threadIdx.x;
    int to = t & 15, tm = t >> 4;
    __shared__ float Ys[16 * 34];
    __shared__ float Fs[16 * 68];
    float acc[2][4] = {};
    int n0 = bn * 32, d0 = bd * 64, kbase = bk * 256;
    for (int c0 = kbase; c0 < kbase + 256; c0 += 16) {
#pragma unroll
        for (int i = 0; i < 2; ++i) {
            int e = i * 256 + t;
            int m = e >> 4, k = e & 15;
            Ys[k * 34 + m] = Y[(size_t)(n0 + m) * 4096 + c0 + k];
        }
#pragma unroll
        for (int i = 0; i < 4; ++i) {
            int e = i * 256 + t;
            int d = e >> 4, k = e & 15;
            Fs[k * 68 + d] = Fw[(size_t)(d0 + d) * 4096 + c0 + k];
        }
        __syncthreads();
#pragma unroll
        for (int k = 0; k < 16; ++k) {
            float2 a = *(const float2*)&Ys[k * 34 + tm * 2];
            float4 b = *(const float4*)&Fs[k * 68 + to * 4];
            acc[0][0] += a.x * b.x; acc[0][1] += a.x * b.y;
            acc[0][2] += a.x * b.z; acc[0][3] += a.x * b.w;
            acc[1][0] += a.y * b.x; acc[1][1] += a.y * b.y;
            acc[1][2] += a.y * b.z; acc[1][3] += a.y * b.w;
        }
        __syncthreads();
    }
#pragma unroll
    for (int i = 0; i < 2; ++i) {
        int nn = n0 + tm * 2 + i;
#pragma unroll
        for (int j = 0; j < 4; ++j) {
            int d = d0 + to * 4 + j;
            atomicAdd(&out[(size_t)nn * 512 + d], acc[i][j]);
        }
    }
}

// ---------------------------------------------------------------------------
extern "C" void kernel_launch(void* const* d_in, const int* in_sizes, int n_in,
                              void* d_out, int out_size, void* d_ws, size_t ws_size,
                              hipStream_t stream) {
    const float* snd    = (const float*)d_in[0];
    const float* conv_w = (const float*)d_in[1];
    const float* conv_b = (const float*)d_in[2];
    const float* fc_w   = (const float*)d_in[3];
    const float* fc_b   = (const float*)d_in[4];
    float* out = (float*)d_out;
    float* ws  = (float*)d_ws;

    float*  partial = ws + WS_PARTIAL;
    int*    pos     = (int*)(ws + WS_POS);
    float*  lnorm   = ws + WS_LNORM;
    ushort* nodes   = (ushort*)(ws + WS_NODES);
    ushort* Wb      = (ushort*)(ws + WS_WB);
    float*  Xpart   = ws + WS_XPART;
    float*  Y       = ws + WS_Y;

    k_prep<<<768, 256, 0, stream>>>(conv_w, Wb, fc_b, out);
    k_reduce<<<dim3(128, 8), 256, 0, stream>>>(snd, partial);
    k_topk_lnorm<<<128, 256, 0, stream>>>(partial, pos, lnorm);
    k_gather<<<dim3(128, 64), 256, 0, stream>>>(snd, pos, nodes);
    k_conv<<<dim3(32, 4, 8), 256, 0, stream>>>(nodes, Wb, Xpart);
    k_xmix<<<128, 256, 0, stream>>>(Xpart, conv_b, lnorm, Y);
    k_fc<<<dim3(4, 8, 16), 256, 0, stream>>>(Y, fc_w, out);
}

// Round 3
// 432.750 us; speedup vs baseline: 1.1248x; 1.0962x over previous
//
#include <hip/hip_runtime.h>
#include <math.h>

typedef __attribute__((ext_vector_type(8))) short short8;
typedef __attribute__((ext_vector_type(4))) float f32x4;
typedef unsigned short ushort;
typedef unsigned int uint;

// Problem constants
#define NB   128
#define CIN  2048
#define PP   256
#define KK   16
#define CO   256
#define DO   512

// ws layout (float offsets)
#define WS_FRE   0          // [128][256] fp32 channel-sums = 32768 floats
#define WS_POS   32768      // 2048 ints
#define WS_LNORM 34816      // 32768 floats -> end 67584
#define WS_WG    67584      // bf16 [256 o][2048 c] = 524288 ushorts = 262144 floats
#define WS_XALL  329728     // [128 n][256 pos][256 o] fp32 = 8,388,608 floats
#define WS_Y     8718336    // [128][4096] fp32 = 524,288 floats -> end 9242624

__device__ __forceinline__ ushort f2bf(float f) {
    uint u = __builtin_bit_cast(uint, f);
    u += 0x7fffu + ((u >> 16) & 1u);   // RNE (inputs are normal floats)
    return (ushort)(u >> 16);
}

// ---------------------------------------------------------------------------
// K0: prep — conv_w -> bf16 with per-row chunk swizzle (so global_load_lds
// linear staging + XOR'd LDS reads are conflict-free), and init out with fc
// bias. Swizzle: within each 64-elem chunk-group, chunk s of row o stored at
// s ^ x(o), x(o) = (o ^ (o>>3)) & 7. grid 768.
__global__ __launch_bounds__(256) void k_prep(const float* __restrict__ conv_w,
                                              ushort* __restrict__ Wg,
                                              const float* __restrict__ fcb,
                                              float* __restrict__ out) {
    int b = blockIdx.x, t = threadIdx.x;
    if (b < 512) {
        int e0 = (b * 256 + t) * 4;          // element index
        int o  = e0 >> 11;
        int c  = e0 & 2047;
        int x  = ((o ^ (o >> 3)) & 7) << 3;  // element-XOR (bits 3..5)
        int cs = c ^ x;
        float4 v = *(const float4*)(conv_w + e0);
        uint2 u;
        u.x = (uint)f2bf(v.x) | ((uint)f2bf(v.y) << 16);
        u.y = (uint)f2bf(v.z) | ((uint)f2bf(v.w) << 16);
        *(uint2*)(Wg + (size_t)o * 2048 + cs) = u;
    } else {
        int i = (b - 512) * 256 + t;
        out[i] = fcb[i & 511];
    }
}

// ---------------------------------------------------------------------------
// K1: fused all-positions conv GEMM + channel-sum.
// grid (128 n, 4 pb), block 256 (4 waves). Block computes
// X_all[n][pb*64..+64 pos][256 o] = W @ sounds slab, and fre[n][pb*64..+64]
// (exact fp32 channel sums, free during staging). Streams sounds exactly
// once (256 MB total across grid). W tile via global_load_lds from the
// pre-swizzled Wg; sounds reg-staged into padded fp32 LDS [c][pos]
// (stride 66 dwords -> 2-way banks everywhere).
__global__ __launch_bounds__(256) void k_convall(const float* __restrict__ snd,
                                                 const ushort* __restrict__ Wg,
                                                 float* __restrict__ Xall,
                                                 float* __restrict__ fre) {
    int n = blockIdx.x, pb = blockIdx.y, t = threadIdx.x;
    int w = t >> 6, l = t & 63, lm = l & 15, quad = l >> 4;
    __shared__ ushort As[256 * 64];      // [o][64 c] bf16 (chunk-swizzled), 32 KB
    __shared__ float  Bs[64 * 66];       // [c][pos] fp32, row 66 dwords, 16.9 KB

    f32x4 acc[4][4] = {};                // [ot][pt]
    float4 facc = make_float4(0.f, 0.f, 0.f, 0.f);

    int sg = t >> 4, pos4 = t & 15;      // sounds staging coords
    const float* sbase = snd + (size_t)n * (CIN * PP) + pb * 64;

    // per-lane A constants: o-row, swizzle key, base (ushort units)
    int xsw[4], abase[4];
#pragma unroll
    for (int ot = 0; ot < 4; ++ot) {
        int o = w * 64 + ot * 16 + lm;
        xsw[ot] = (o ^ (o >> 3)) & 7;
        abase[ot] = o * 64;
    }

    for (int it = 0; it < 32; ++it) {
        int c0 = it * 64;
        // ---- stage W tile [256 o][c0..c0+64) via global_load_lds (linear) ----
#pragma unroll
        for (int i = 0; i < 8; ++i) {
            int oo = i * 32 + (t >> 3);
            int seg = t & 7;
            const ushort* src = Wg + (size_t)oo * 2048 + c0 + seg * 8;
            ushort* dst = As + oo * 64 + seg * 8;
            __builtin_amdgcn_global_load_lds(
                (const __attribute__((address_space(1))) uint*)src,
                (__attribute__((address_space(3))) uint*)dst, 16, 0, 0);
        }
        // ---- reg-stage sounds slab [64 c][64 pos] + exact fp32 fre acc ----
        float4 sv[4];
#pragma unroll
        for (int rc = 0; rc < 4; ++rc) {
            int cl = rc * 16 + sg;
            sv[rc] = *(const float4*)(sbase + (size_t)(c0 + cl) * PP + pos4 * 4);
        }
#pragma unroll
        for (int rc = 0; rc < 4; ++rc) {
            facc.x += sv[rc].x; facc.y += sv[rc].y;
            facc.z += sv[rc].z; facc.w += sv[rc].w;
            int cl = rc * 16 + sg;
            float* wp = Bs + cl * 66 + pos4 * 4;
            *(float2*)wp       = make_float2(sv[rc].x, sv[rc].y);
            *(float2*)(wp + 2) = make_float2(sv[rc].z, sv[rc].w);
        }
        __syncthreads();
        // ---- compute: 2 k-substeps of K=32 ----
#pragma unroll
        for (int ks = 0; ks < 2; ++ks) {
            short8 af[4];
#pragma unroll
            for (int ot = 0; ot < 4; ++ot) {
                int seg = (ks * 4 + quad) ^ xsw[ot];
                af[ot] = *(const short8*)(As + abase[ot] + seg * 8);
            }
#pragma unroll
            for (int pt = 0; pt < 4; ++pt) {
                const float* bp = Bs + (ks * 32 + quad * 8) * 66 + pt * 16 + lm;
                uint u0 = (uint)f2bf(bp[0])   | ((uint)f2bf(bp[66])  << 16);
                uint u1 = (uint)f2bf(bp[132]) | ((uint)f2bf(bp[198]) << 16);
                uint u2 = (uint)f2bf(bp[264]) | ((uint)f2bf(bp[330]) << 16);
                uint u3 = (uint)f2bf(bp[396]) | ((uint)f2bf(bp[462]) << 16);
                short8 bf = __builtin_bit_cast(short8, make_uint4(u0, u1, u2, u3));
#pragma unroll
                for (int ot = 0; ot < 4; ++ot)
                    acc[ot][pt] = __builtin_amdgcn_mfma_f32_16x16x32_bf16(
                        af[ot], bf, acc[ot][pt], 0, 0, 0);
            }
        }
        __syncthreads();
    }

    // ---- C write: X_all[n][pos][o], lane: col(pos)=lm, row(o)=quad*4+reg ----
    float* xo = Xall + (size_t)n * 256 * 256;
#pragma unroll
    for (int ot = 0; ot < 4; ++ot) {
#pragma unroll
        for (int pt = 0; pt < 4; ++pt) {
            int pos = pb * 64 + pt * 16 + lm;
            int o   = w * 64 + ot * 16 + quad * 4;
            *(float4*)(xo + (size_t)pos * 256 + o) =
                make_float4(acc[ot][pt][0], acc[ot][pt][1], acc[ot][pt][2], acc[ot][pt][3]);
        }
    }

    // ---- fre: reduce 16 channel-groups via LDS (reuse As as scratch) ----
    float* scr = (float*)As;
    *(float4*)(scr + sg * 64 + pos4 * 4) = facc;
    __syncthreads();
    if (t < 64) {
        float s = 0.f;
#pragma unroll
        for (int g = 0; g < 16; ++g) s += scr[g * 64 + t];
        fre[n * 256 + pb * 64 + t] = s;
    }
}

// ---------------------------------------------------------------------------
// K2: top-16 (shuffle butterfly), remap, lnorm. grid 128.
__global__ __launch_bounds__(256) void k_topk_lnorm(const float* __restrict__ fre,
                                                    int* __restrict__ pos,
                                                    float* __restrict__ lnorm) {
    int n = blockIdx.x, t = threadIdx.x;
    int lane = t & 63, wv = t >> 6;
    __shared__ float wval[4];
    __shared__ int   widx[4];
    __shared__ int   sel[16];
    __shared__ float rr[16], cc[16], dinv[16];
    __shared__ float Ash[256];

    float v = fre[n * 256 + t];

    for (int k = 0; k < 16; ++k) {
        float bv = v; int bi = t;
#pragma unroll
        for (int off = 32; off > 0; off >>= 1) {
            float ov = __shfl_xor(bv, off, 64);
            int   oi = __shfl_xor(bi, off, 64);
            if (ov > bv || (ov == bv && oi < bi)) { bv = ov; bi = oi; }
        }
        if (lane == 0) { wval[wv] = bv; widx[wv] = bi; }
        __syncthreads();
        float best = wval[0]; int besti = widx[0];
#pragma unroll
        for (int w = 1; w < 4; ++w) {
            float ww = wval[w]; int wi = widx[w];
            if (ww > best || (ww == best && wi < besti)) { best = ww; besti = wi; }
        }
        if (t == besti) v = -INFINITY;
        if (t == 0) sel[k] = besti;
        __syncthreads();
    }

    if (t < 16) {
        int idx = sel[t];
        int r = (idx < 16) ? (idx >> 4) : ((idx >> 4) - 1);
        int c = ((idx & 15) == 0) ? 15 : ((idx & 15) - 1);
        pos[n * 16 + t] = r * 16 + c;
        rr[t] = (float)r; cc[t] = (float)c;
    }
    __syncthreads();
    {
        int i = t >> 4, j = t & 15;
        float dr = rr[i] - rr[j], dc = cc[i] - cc[j];
        Ash[t] = expf(-(dr * dr + dc * dc) * (1.0f / 32.0f));
    }
    __syncthreads();
    if (t < 16) {
        float srow = 0.f;
#pragma unroll
        for (int j = 0; j < 16; ++j) srow += Ash[t * 16 + j];
        dinv[t] = rsqrtf(srow);
    }
    __syncthreads();
    {
        int i = t >> 4, j = t & 15;
        lnorm[(size_t)n * 256 + t] = Ash[t] * dinv[i] * dinv[j];
    }
}

// ---------------------------------------------------------------------------
// K3: select 16 positions from X_all, bias+relu, lnorm mix -> Y. grid 128.
__global__ __launch_bounds__(256) void k_xsel(const float* __restrict__ Xall,
                                              const int* __restrict__ pos,
                                              const float* __restrict__ bias,
                                              const float* __restrict__ lnorm,
                                              float* __restrict__ Y) {
    int n = blockIdx.x, o = threadIdx.x;
    __shared__ float ln[256];
    __shared__ int lp[16];
    ln[o] = lnorm[(size_t)n * 256 + o];
    if (o < 16) lp[o] = pos[n * 16 + o];
    float b = bias[o];
    __syncthreads();
    float xv[16];
#pragma unroll
    for (int j = 0; j < 16; ++j) {
        xv[j] = fmaxf(Xall[((size_t)n * 256 + lp[j]) * 256 + o] + b, 0.0f);
    }
#pragma unroll
    for (int i = 0; i < 16; ++i) {
        float a = 0.f;
#pragma unroll
        for (int j = 0; j < 16; ++j) a += ln[i * 16 + j] * xv[j];
        Y[(size_t)n * 4096 + i * 256 + o] = a;
    }
}

// ---------------------------------------------------------------------------
// K4: fc GEMM split-K fp32, atomic accumulate onto bias-initialized out.
// grid (4, 8, 16) = 512 blocks = 2 blocks/CU.
__global__ __launch_bounds__(256) void k_fc(const float* __restrict__ Y,
                                            const float* __restrict__ Fw,
                                            float* __restrict__ out) {
    int bn = blockIdx.x, bd = blockIdx.y, bk = blockIdx.z, t = threadIdx.x;
    int to = t & 15, tm = t >> 4;
    __shared__ float Ys[16 * 34];
    __shared__ float Fs[16 * 68];
    float acc[2][4] = {};
    int n0 = bn * 32, d0 = bd * 64, kbase = bk * 256;
    for (int c0 = kbase; c0 < kbase + 256; c0 += 16) {
#pragma unroll
        for (int i = 0; i < 2; ++i) {
            int e = i * 256 + t;
            int m = e >> 4, k = e & 15;
            Ys[k * 34 + m] = Y[(size_t)(n0 + m) * 4096 + c0 + k];
        }
#pragma unroll
        for (int i = 0; i < 4; ++i) {
            int e = i * 256 + t;
            int d = e >> 4, k = e & 15;
            Fs[k * 68 + d] = Fw[(size_t)(d0 + d) * 4096 + c0 + k];
        }
        __syncthreads();
#pragma unroll
        for (int k = 0; k < 16; ++k) {
            float2 a = *(const float2*)&Ys[k * 34 + tm * 2];
            float4 b = *(const float4*)&Fs[k * 68 + to * 4];
            acc[0][0] += a.x * b.x; acc[0][1] += a.x * b.y;
            acc[0][2] += a.x * b.z; acc[0][3] += a.x * b.w;
            acc[1][0] += a.y * b.x; acc[1][1] += a.y * b.y;
            acc[1][2] += a.y * b.z; acc[1][3] += a.y * b.w;
        }
        __syncthreads();
    }
#pragma unroll
    for (int i = 0; i < 2; ++i) {
        int nn = n0 + tm * 2 + i;
#pragma unroll
        for (int j = 0; j < 4; ++j) {
            int d = d0 + to * 4 + j;
            atomicAdd(&out[(size_t)nn * 512 + d], acc[i][j]);
        }
    }
}

// ---------------------------------------------------------------------------
extern "C" void kernel_launch(void* const* d_in, const int* in_sizes, int n_in,
                              void* d_out, int out_size, void* d_ws, size_t ws_size,
                              hipStream_t stream) {
    const float* snd    = (const float*)d_in[0];
    const float* conv_w = (const float*)d_in[1];
    const float* conv_b = (const float*)d_in[2];
    const float* fc_w   = (const float*)d_in[3];
    const float* fc_b   = (const float*)d_in[4];
    float* out = (float*)d_out;
    float* ws  = (float*)d_ws;

    float*  fre   = ws + WS_FRE;
    int*    pos   = (int*)(ws + WS_POS);
    float*  lnorm = ws + WS_LNORM;
    ushort* Wg    = (ushort*)(ws + WS_WG);
    float*  Xall  = ws + WS_XALL;
    float*  Y     = ws + WS_Y;

    k_prep<<<768, 256, 0, stream>>>(conv_w, Wg, fc_b, out);
    k_convall<<<dim3(128, 4), 256, 0, stream>>>(snd, Wg, Xall, fre);
    k_topk_lnorm<<<128, 256, 0, stream>>>(fre, pos, lnorm);
    k_xsel<<<128, 256, 0, stream>>>(Xall, pos, conv_b, lnorm, Y);
    k_fc<<<dim3(4, 8, 16), 256, 0, stream>>>(Y, fc_w, out);
}